// Round 20
// baseline (211.291 us; speedup 1.0000x reference)
//
#include <hip/hip_runtime.h>
#include <hip/hip_bf16.h>
#include <cstdint>

typedef __attribute__((ext_vector_type(8))) short bf16x8;
typedef __attribute__((ext_vector_type(4))) float f32x4;

#define PLDT 72   // attn P^T LDS row stride

static __device__ __forceinline__ unsigned short f2bf(float x) {
    __hip_bfloat16 h = __float2bfloat16(x);
    union { __hip_bfloat16 b; unsigned short u; } c; c.b = h; return c.u;
}
static __device__ __forceinline__ float bf2f(unsigned short b) {
    union { float f; uint32_t u; } v; v.u = ((uint32_t)b) << 16;
    return v.f;
}
static __device__ __forceinline__ float exp2b(float x) {
    return __builtin_amdgcn_exp2f(x);
}
static __device__ __forceinline__ unsigned int cvt_pk_bf16(float lo, float hi) {
    unsigned int r;
    asm("v_cvt_pk_bf16_f32 %0, %1, %2" : "=v"(r) : "v"(lo), "v"(hi));
    return r;
}
static __device__ __forceinline__ void gload_lds16(const unsigned short* g, unsigned short* l) {
    __builtin_amdgcn_global_load_lds(
        (const __attribute__((address_space(1))) void*)g,
        (__attribute__((address_space(3))) void*)l, 16, 0, 0);
}

// ---------------------------------------------------------------------------
// fp32 -> bf16 convert pass (unchanged).
// ---------------------------------------------------------------------------
__global__ __launch_bounds__(256) void cvt_all(
    const float* __restrict__ xq, const float* __restrict__ xk, const float* __restrict__ xv,
    const float* __restrict__ wq, const float* __restrict__ wk, const float* __restrict__ wv,
    unsigned short* __restrict__ oxq, unsigned short* __restrict__ oxk, unsigned short* __restrict__ oxv,
    unsigned short* __restrict__ owq, unsigned short* __restrict__ owk, unsigned short* __restrict__ owv) {
    const int z = blockIdx.z;
    const float* in = (z == 0) ? xq : (z == 1) ? xk : (z == 2) ? xv
                      : (z == 3) ? wq : (z == 4) ? wk : wv;
    unsigned short* out = (z == 0) ? oxq : (z == 1) ? oxk : (z == 2) ? oxv
                          : (z == 3) ? owq : (z == 4) ? owk : owv;
    const int n8 = (z < 3) ? 524288 : 131072;
    int i = blockIdx.x * 256 + threadIdx.x;
    if (i >= n8) return;
    const float4* ip = (const float4*)in;
    float4 a = ip[2 * i];
    float4 b = ip[2 * i + 1];
    uint4 r;
    r.x = cvt_pk_bf16(a.x, a.y);
    r.y = cvt_pk_bf16(a.z, a.w);
    r.z = cvt_pk_bf16(b.x, b.y);
    r.w = cvt_pk_bf16(b.z, b.w);
    *(uint4*)(out + (size_t)i * 8) = r;
}

// ---------------------------------------------------------------------------
// Projection GEMM, m97 structure (r13 version). z=0: Q row-major;
// z=1: K and z=2: V^T in 16x16x32 MFMA fragment order.
// ---------------------------------------------------------------------------
__global__ __launch_bounds__(256) void proj_gemm_bf16(
    const unsigned short* __restrict__ Xqb, const unsigned short* __restrict__ Xkb,
    const unsigned short* __restrict__ Xvb,
    const unsigned short* __restrict__ Wqb, const unsigned short* __restrict__ Wkb,
    const unsigned short* __restrict__ Wvb,
    const float* __restrict__ bqp, const float* __restrict__ bkp, const float* __restrict__ bvp,
    unsigned short* __restrict__ dq, unsigned short* __restrict__ dk, unsigned short* __restrict__ dv) {
    __shared__ unsigned short a_lds[128 * 64];
    __shared__ unsigned short b_lds[128 * 64];

    const int z = blockIdx.z;
    const unsigned short* X = (z == 0) ? Xqb : (z == 1) ? Xkb : Xvb;
    const unsigned short* W = (z == 0) ? Wqb : (z == 1) ? Wkb : Wvb;
    const float* bias = (z == 0) ? bqp : (z == 1) ? bkp : bvp;
    unsigned short* dst = (z == 0) ? dq : (z == 1) ? dk : dv;

    const int tid = threadIdx.x;
    const int lane = tid & 63;
    const int w = tid >> 6;
    const int lr = lane & 15;
    const int lg = lane >> 4;
    const int m0 = blockIdx.x * 128;
    const int e0 = blockIdx.y * 128;
    const int wrow = (w >> 1) * 64;
    const int wcol = (w & 1) * 64;

    f32x4 acc[4][4] = {};

#pragma unroll 1
    for (int t = 0; t < 16; ++t) {
        const int k0 = t * 64;
        __syncthreads();
#pragma unroll
        for (int i = 0; i < 4; ++i) {
            int c = i * 256 + w * 64 + lane;
            int row = c >> 3;
            int col = (c & 7) * 8;
            gload_lds16(X + (size_t)(m0 + row) * 1024 + k0 + col,
                        a_lds + (size_t)(i * 256 + w * 64) * 8);
            gload_lds16(W + (size_t)(e0 + row) * 1024 + k0 + col,
                        b_lds + (size_t)(i * 256 + w * 64) * 8);
        }
        __syncthreads();

#pragma unroll
        for (int ks = 0; ks < 2; ++ks) {
            const int kk = ks * 32 + lg * 8;
            bf16x8 af[4], bfr[4];
#pragma unroll
            for (int mt = 0; mt < 4; ++mt)
                af[mt] = *(const bf16x8*)(a_lds + (wrow + mt * 16 + lr) * 64 + kk);
#pragma unroll
            for (int nt = 0; nt < 4; ++nt)
                bfr[nt] = *(const bf16x8*)(b_lds + (wcol + nt * 16 + lr) * 64 + kk);
            __builtin_amdgcn_s_setprio(1);
#pragma unroll
            for (int mt = 0; mt < 4; ++mt)
#pragma unroll
                for (int nt = 0; nt < 4; ++nt)
                    acc[mt][nt] = __builtin_amdgcn_mfma_f32_16x16x32_bf16(
                        af[mt], bfr[nt], acc[mt][nt], 0, 0, 0);
            __builtin_amdgcn_s_setprio(0);
        }
    }

    for (int mt = 0; mt < 4; ++mt)
        for (int nt = 0; nt < 4; ++nt)
            for (int i = 0; i < 4; ++i) {
                int m = m0 + wrow + mt * 16 + lg * 4 + i;
                int e = e0 + wcol + nt * 16 + lr;
                float val = acc[mt][nt][i] + bias[e];
                int b = m >> 11, s = m & 2047;
                int h = e >> 6, d = e & 63;
                size_t headoff = (((size_t)b * 16 + h) * 131072);
                if (z == 0) {
                    dst[headoff + (size_t)s * 64 + d] = f2bf(val);
                } else if (z == 1) {
                    int tt = s >> 6, kvr = s & 63;
                    int fmt = kvr >> 4, flr = kvr & 15;
                    int ks = d >> 5, lg3 = (d >> 3) & 3, j = d & 7;
                    dst[headoff + tt * 4096 + (ks * 4 + fmt) * 512 + (lg3 * 16 + flr) * 8 + j] = f2bf(val);
                } else {
                    int tt = s >> 6, kvc = s & 63;
                    int fmt = d >> 4, flr = d & 15;
                    int ks = kvc >> 5, lg3 = (kvc >> 3) & 3, j = kvc & 7;
                    dst[headoff + tt * 4096 + (ks * 4 + fmt) * 512 + (lg3 * 16 + flr) * 8 + j] = f2bf(val);
                }
            }
}

// ---------------------------------------------------------------------------
// Flash attention v17 (r19 retry; crash was a norm_out grid bug, fixed below).
// = round-13 loop body (PASSING best) + KV-RANGE SPLIT for occupancy:
// 1024 blocks, each handles 16 of 32 kv-tiles -> 4 waves/SIMD.
// No-max softmax makes O-numerator and lsum PURE SUMS over kv: the two
// half-blocks atomically accumulate unnormalized O into the pre-zeroed
// output and lsum into a ws buffer (exactly 2 commutative f32 adds per
// location -> bitwise deterministic). norm_out divides afterwards.
// ---------------------------------------------------------------------------
__global__ __launch_bounds__(256) void attn_kernel(
    const unsigned short* __restrict__ Qh,
    const unsigned short* __restrict__ Kf,
    const unsigned short* __restrict__ Vf,
    const unsigned char* __restrict__ mask,
    float* __restrict__ Out,
    float* __restrict__ lsums) {
    __shared__ unsigned short pbuf[4][32 * PLDT];  // per-wave P [32 q][64 kv]

    const int tid = threadIdx.x;
    const int lane = tid & 63;
    const int w = tid >> 6;
    const int lr = lane & 15;
    const int lg = lane >> 4;

    // T1 XCD swizzle: 1024 workgroups, 128 per XCD. One XCD covers 4 heads
    // (both kv halves, all 16 q-tiles) -> 2MB KV working set per XCD L2.
    const int bid = blockIdx.x;
    const int wk = (bid & 7) * 128 + (bid >> 3);
    const int x = wk & 15;            // q-tile
    const int kvh = (wk >> 4) & 1;    // kv half
    const int bh = wk >> 5;           // 0..31
    const int h = bh & 15;
    const int b = bh >> 4;
    const int q0 = x * 128;

    const size_t headoff = (((size_t)b * 16) + h) * 131072;
    const unsigned short* Qp = Qh + headoff;
    const unsigned char* maskp = mask + b * 2048;
    unsigned short* pw = pbuf[w];

    const unsigned short* kfb = Kf + headoff + (size_t)lane * 8;
    const unsigned short* vfb = Vf + headoff + (size_t)lane * 8;

    // Q as B-operand (col=q=lr, k=lg*8+j), scaled by 1/sqrt(64)*log2(e)
    const float qscale = 0.125f * 1.44269504088896340736f;
    bf16x8 qf[2][2];
#pragma unroll
    for (int qh = 0; qh < 2; ++qh) {
        int row = q0 + w * 32 + qh * 16 + lr;
#pragma unroll
        for (int ks = 0; ks < 2; ++ks) {
            bf16x8 t = *(const bf16x8*)(Qp + (size_t)row * 64 + ks * 32 + lg * 8);
#pragma unroll
            for (int j = 0; j < 8; ++j)
                t[j] = (short)f2bf(bf2f((unsigned short)t[j]) * qscale);
            qf[qh][ks] = t;
        }
    }

    f32x4 o[2][4] = {};           // O^T partial: lane holds q=lr
    float lsum[2] = {0.f, 0.f};

    const int t0 = kvh * 16;
#pragma unroll 1
    for (int t = t0; t < t0 + 16; ++t) {
        const int kv0 = t * 64;
        const unsigned short* kt = kfb + t * 4096;
        const unsigned short* vt = vfb + t * 4096;

        bf16x8 kf[2][4];
#pragma unroll
        for (int ks = 0; ks < 2; ++ks)
#pragma unroll
            for (int mt = 0; mt < 4; ++mt)
                kf[ks][mt] = *(const bf16x8*)(kt + (ks * 4 + mt) * 512);

        f32x4 s[2][4] = {};
        __builtin_amdgcn_s_setprio(1);
#pragma unroll
        for (int ks = 0; ks < 2; ++ks)
#pragma unroll
            for (int mt = 0; mt < 4; ++mt) {
                s[0][mt] = __builtin_amdgcn_mfma_f32_16x16x32_bf16(kf[ks][mt], qf[0][ks], s[0][mt], 0, 0, 0);
                s[1][mt] = __builtin_amdgcn_mfma_f32_16x16x32_bf16(kf[ks][mt], qf[1][ks], s[1][mt], 0, 0, 0);
            }
        __builtin_amdgcn_s_setprio(0);

        bf16x8 vf[2][4];
#pragma unroll
        for (int ks = 0; ks < 2; ++ks)
#pragma unroll
            for (int mt = 0; mt < 4; ++mt)
                vf[ks][mt] = *(const bf16x8*)(vt + (ks * 4 + mt) * 512);

        unsigned long long mbits = __ballot(maskp[kv0 + lane] != 0);
        if (mbits) {
#pragma unroll
            for (int qh = 0; qh < 2; ++qh)
#pragma unroll
                for (int mt = 0; mt < 4; ++mt)
#pragma unroll
                    for (int i = 0; i < 4; ++i)
                        if ((mbits >> (mt * 16 + lg * 4 + i)) & 1ull) s[qh][mt][i] = -1e30f;
        }

#pragma unroll
        for (int qh = 0; qh < 2; ++qh) {
            float p[4][4];
            float ls = 0.f;
#pragma unroll
            for (int mt = 0; mt < 4; ++mt)
#pragma unroll
                for (int i = 0; i < 4; ++i) {
                    p[mt][i] = exp2b(s[qh][mt][i]);
                    ls += p[mt][i];
                }
            ls += __shfl_xor(ls, 16);
            ls += __shfl_xor(ls, 32);
            lsum[qh] += ls;

#pragma unroll
            for (int mt = 0; mt < 4; ++mt) {
                uint2 pr;
                pr.x = cvt_pk_bf16(p[mt][0], p[mt][1]);
                pr.y = cvt_pk_bf16(p[mt][2], p[mt][3]);
                *(uint2*)(&pw[(qh * 16 + lr) * PLDT + mt * 16 + lg * 4]) = pr;
            }
        }

        __builtin_amdgcn_s_setprio(1);
#pragma unroll
        for (int qh = 0; qh < 2; ++qh)
#pragma unroll
            for (int ks = 0; ks < 2; ++ks) {
                bf16x8 pfr = *(const bf16x8*)(&pw[(qh * 16 + lr) * PLDT + ks * 32 + lg * 8]);
#pragma unroll
                for (int mt = 0; mt < 4; ++mt)
                    o[qh][mt] = __builtin_amdgcn_mfma_f32_16x16x32_bf16(vf[ks][mt], pfr, o[qh][mt], 0, 0, 0);
            }
        __builtin_amdgcn_s_setprio(0);
    }

    // epilogue: UNNORMALIZED partial -> transpose in LDS -> atomic adds.
    float* ep = (float*)pw;
#pragma unroll
    for (int qh = 0; qh < 2; ++qh) {
        if (lane < 16)
            atomicAdd(&lsums[(size_t)bh * 2048 + q0 + w * 32 + qh * 16 + lane], lsum[qh]);
#pragma unroll
        for (int mt = 0; mt < 4; ++mt)
#pragma unroll
            for (int i = 0; i < 4; ++i)
                ep[lr * 68 + mt * 16 + lg * 4 + i] = o[qh][mt][i];
#pragma unroll
        for (int j = 0; j < 4; ++j) {
            int id = lane + 64 * j;
            int row = id >> 4;
            int c4 = (id & 15) << 2;
            float4 val = *(const float4*)(&ep[row * 68 + c4]);
            float* dst = &Out[((size_t)b * 2048 + q0 + w * 32 + qh * 16 + row) * 1024 + h * 64 + c4];
            atomicAdd(dst + 0, val.x);
            atomicAdd(dst + 1, val.y);
            atomicAdd(dst + 2, val.z);
            atomicAdd(dst + 3, val.w);
        }
    }
}

// ---------------------------------------------------------------------------
// Normalize: out[b][s][h*64+d] /= lsums[(b*16+h)*2048 + s].  In-place, f32x4.
// N_FLOAT4 = out_size/4 = 1048576; grid 4096 x 256 (r19's grid was 4x too
// big -> OOB fault; fixed + guarded).
// ---------------------------------------------------------------------------
__global__ __launch_bounds__(256) void norm_out(float* __restrict__ out,
                                                const float* __restrict__ lsums) {
    int i = blockIdx.x * 256 + threadIdx.x;   // float4 index
    if (i >= 1048576) return;
    int m = i >> 8;                           // b*2048 + s  (1024 floats/row)
    int h = (i >> 4) & 15;
    int b = m >> 11, s = m & 2047;
    float l = lsums[(((size_t)b * 16) + h) * 2048 + s];
    float r = 1.0f / l;
    float4 v = ((float4*)out)[i];
    v.x *= r; v.y *= r; v.z *= r; v.w *= r;
    ((float4*)out)[i] = v;
}

extern "C" void kernel_launch(void* const* d_in, const int* in_sizes, int n_in,
                              void* d_out, int out_size, void* d_ws, size_t ws_size,
                              hipStream_t stream) {
    const float* v = (const float*)d_in[0];
    const float* k = (const float*)d_in[1];
    const float* q = (const float*)d_in[2];
    const unsigned char* mask = (const unsigned char*)d_in[3];
    const float* Wq = (const float*)d_in[4];
    const float* bq = (const float*)d_in[5];
    const float* Wk = (const float*)d_in[6];
    const float* bk = (const float*)d_in[7];
    const float* Wv = (const float*)d_in[8];
    const float* bv = (const float*)d_in[9];
    float* out = (float*)d_out;

    unsigned short* ws = (unsigned short*)d_ws;
    unsigned short* qh  = ws;                 // 4096*1024 each
    unsigned short* kh  = ws + 4194304;       // K in fragment order
    unsigned short* vT  = ws + 8388608;       // V^T in fragment order
    unsigned short* xqb = ws + 12582912;      // bf16 X inputs
    unsigned short* xkb = ws + 16777216;
    unsigned short* xvb = ws + 20971520;
    unsigned short* wqb = ws + 25165824;      // bf16 W inputs (dead after proj)
    unsigned short* wkb = ws + 26214400;
    unsigned short* wvb = ws + 27262976;
    // lsums lives in the wqb region (dead after proj_gemm reads it);
    // zeroed AFTER proj, stream-ordered. Keeps ws footprint at the proven max.
    float* lsums = (float*)wqb;               // 65536 f32 = 256KB <= 2MB region

    hipMemsetAsync(out, 0, (size_t)out_size * sizeof(float), stream);

    cvt_all<<<dim3(2048, 1, 6), 256, 0, stream>>>(q, k, v, Wq, Wk, Wv,
                                                  xqb, xkb, xvb, wqb, wkb, wvb);

    dim3 pgrid(32, 8, 3);
    proj_gemm_bf16<<<pgrid, 256, 0, stream>>>(xqb, xkb, xvb, wqb, wkb, wvb,
                                              bq, bk, bv, qh, kh, vT);

    hipMemsetAsync(lsums, 0, 65536 * sizeof(float), stream);

    attn_kernel<<<dim3(1024), 256, 0, stream>>>(qh, kh, vT, mask, out, lsums);

    norm_out<<<dim3(4096), 256, 0, stream>>>(out, lsums);
}

// Round 21
// 114.933 us; speedup vs baseline: 1.8384x; 1.8384x over previous
//
#include <hip/hip_runtime.h>
#include <hip/hip_bf16.h>
#include <cstdint>

typedef __attribute__((ext_vector_type(8))) short bf16x8;
typedef __attribute__((ext_vector_type(4))) float f32x4;

#define PLDT 72   // attn P^T LDS row stride

static __device__ __forceinline__ unsigned short f2bf(float x) {
    __hip_bfloat16 h = __float2bfloat16(x);
    union { __hip_bfloat16 b; unsigned short u; } c; c.b = h; return c.u;
}
static __device__ __forceinline__ float bf2f(unsigned short b) {
    union { float f; uint32_t u; } v; v.u = ((uint32_t)b) << 16;
    return v.f;
}
static __device__ __forceinline__ float exp2b(float x) {
    return __builtin_amdgcn_exp2f(x);
}
static __device__ __forceinline__ unsigned int cvt_pk_bf16(float lo, float hi) {
    unsigned int r;
    asm("v_cvt_pk_bf16_f32 %0, %1, %2" : "=v"(r) : "v"(lo), "v"(hi));
    return r;
}
static __device__ __forceinline__ void gload_lds16(const unsigned short* g, unsigned short* l) {
    __builtin_amdgcn_global_load_lds(
        (const __attribute__((address_space(1))) void*)g,
        (__attribute__((address_space(3))) void*)l, 16, 0, 0);
}

// ---------------------------------------------------------------------------
// fp32 -> bf16 convert pass (unchanged).
// ---------------------------------------------------------------------------
__global__ __launch_bounds__(256) void cvt_all(
    const float* __restrict__ xq, const float* __restrict__ xk, const float* __restrict__ xv,
    const float* __restrict__ wq, const float* __restrict__ wk, const float* __restrict__ wv,
    unsigned short* __restrict__ oxq, unsigned short* __restrict__ oxk, unsigned short* __restrict__ oxv,
    unsigned short* __restrict__ owq, unsigned short* __restrict__ owk, unsigned short* __restrict__ owv) {
    const int z = blockIdx.z;
    const float* in = (z == 0) ? xq : (z == 1) ? xk : (z == 2) ? xv
                      : (z == 3) ? wq : (z == 4) ? wk : wv;
    unsigned short* out = (z == 0) ? oxq : (z == 1) ? oxk : (z == 2) ? oxv
                          : (z == 3) ? owq : (z == 4) ? owk : owv;
    const int n8 = (z < 3) ? 524288 : 131072;
    int i = blockIdx.x * 256 + threadIdx.x;
    if (i >= n8) return;
    const float4* ip = (const float4*)in;
    float4 a = ip[2 * i];
    float4 b = ip[2 * i + 1];
    uint4 r;
    r.x = cvt_pk_bf16(a.x, a.y);
    r.y = cvt_pk_bf16(a.z, a.w);
    r.z = cvt_pk_bf16(b.x, b.y);
    r.w = cvt_pk_bf16(b.z, b.w);
    *(uint4*)(out + (size_t)i * 8) = r;
}

// ---------------------------------------------------------------------------
// Projection GEMM, m97 structure (r13 version). z=0: Q row-major;
// z=1: K and z=2: V^T in 16x16x32 MFMA fragment order.
// ---------------------------------------------------------------------------
__global__ __launch_bounds__(256) void proj_gemm_bf16(
    const unsigned short* __restrict__ Xqb, const unsigned short* __restrict__ Xkb,
    const unsigned short* __restrict__ Xvb,
    const unsigned short* __restrict__ Wqb, const unsigned short* __restrict__ Wkb,
    const unsigned short* __restrict__ Wvb,
    const float* __restrict__ bqp, const float* __restrict__ bkp, const float* __restrict__ bvp,
    unsigned short* __restrict__ dq, unsigned short* __restrict__ dk, unsigned short* __restrict__ dv) {
    __shared__ unsigned short a_lds[128 * 64];
    __shared__ unsigned short b_lds[128 * 64];

    const int z = blockIdx.z;
    const unsigned short* X = (z == 0) ? Xqb : (z == 1) ? Xkb : Xvb;
    const unsigned short* W = (z == 0) ? Wqb : (z == 1) ? Wkb : Wvb;
    const float* bias = (z == 0) ? bqp : (z == 1) ? bkp : bvp;
    unsigned short* dst = (z == 0) ? dq : (z == 1) ? dk : dv;

    const int tid = threadIdx.x;
    const int lane = tid & 63;
    const int w = tid >> 6;
    const int lr = lane & 15;
    const int lg = lane >> 4;
    const int m0 = blockIdx.x * 128;
    const int e0 = blockIdx.y * 128;
    const int wrow = (w >> 1) * 64;
    const int wcol = (w & 1) * 64;

    f32x4 acc[4][4] = {};

#pragma unroll 1
    for (int t = 0; t < 16; ++t) {
        const int k0 = t * 64;
        __syncthreads();
#pragma unroll
        for (int i = 0; i < 4; ++i) {
            int c = i * 256 + w * 64 + lane;
            int row = c >> 3;
            int col = (c & 7) * 8;
            gload_lds16(X + (size_t)(m0 + row) * 1024 + k0 + col,
                        a_lds + (size_t)(i * 256 + w * 64) * 8);
            gload_lds16(W + (size_t)(e0 + row) * 1024 + k0 + col,
                        b_lds + (size_t)(i * 256 + w * 64) * 8);
        }
        __syncthreads();

#pragma unroll
        for (int ks = 0; ks < 2; ++ks) {
            const int kk = ks * 32 + lg * 8;
            bf16x8 af[4], bfr[4];
#pragma unroll
            for (int mt = 0; mt < 4; ++mt)
                af[mt] = *(const bf16x8*)(a_lds + (wrow + mt * 16 + lr) * 64 + kk);
#pragma unroll
            for (int nt = 0; nt < 4; ++nt)
                bfr[nt] = *(const bf16x8*)(b_lds + (wcol + nt * 16 + lr) * 64 + kk);
            __builtin_amdgcn_s_setprio(1);
#pragma unroll
            for (int mt = 0; mt < 4; ++mt)
#pragma unroll
                for (int nt = 0; nt < 4; ++nt)
                    acc[mt][nt] = __builtin_amdgcn_mfma_f32_16x16x32_bf16(
                        af[mt], bfr[nt], acc[mt][nt], 0, 0, 0);
            __builtin_amdgcn_s_setprio(0);
        }
    }

    for (int mt = 0; mt < 4; ++mt)
        for (int nt = 0; nt < 4; ++nt)
            for (int i = 0; i < 4; ++i) {
                int m = m0 + wrow + mt * 16 + lg * 4 + i;
                int e = e0 + wcol + nt * 16 + lr;
                float val = acc[mt][nt][i] + bias[e];
                int b = m >> 11, s = m & 2047;
                int h = e >> 6, d = e & 63;
                size_t headoff = (((size_t)b * 16 + h) * 131072);
                if (z == 0) {
                    dst[headoff + (size_t)s * 64 + d] = f2bf(val);
                } else if (z == 1) {
                    int tt = s >> 6, kvr = s & 63;
                    int fmt = kvr >> 4, flr = kvr & 15;
                    int ks = d >> 5, lg3 = (d >> 3) & 3, j = d & 7;
                    dst[headoff + tt * 4096 + (ks * 4 + fmt) * 512 + (lg3 * 16 + flr) * 8 + j] = f2bf(val);
                } else {
                    int tt = s >> 6, kvc = s & 63;
                    int fmt = d >> 4, flr = d & 15;
                    int ks = kvc >> 5, lg3 = (kvc >> 3) & 3, j = kvc & 7;
                    dst[headoff + tt * 4096 + (ks * 4 + fmt) * 512 + (lg3 * 16 + flr) * 8 + j] = f2bf(val);
                }
            }
}

// ---------------------------------------------------------------------------
// Flash attention v18 = round-13 loop body (PASSING best) + KV-RANGE SPLIT
// with ATOMIC-FREE partial outputs: 1024 blocks (4 waves/SIMD; VGPR ~112
// allows it, grid was the cap), each handles 16 of 32 kv-tiles.
// kvh=0 blocks store unnormalized O to d_out; kvh=1 blocks to a ws partial;
// lsums to two per-half buffers (each location written by exactly ONE block
// -> plain stores, no memset, deterministic). combine_out merges + divides.
// Legal because no-max softmax makes numerator and denominator pure sums.
// ---------------------------------------------------------------------------
__global__ __launch_bounds__(256) void attn_kernel(
    const unsigned short* __restrict__ Qh,
    const unsigned short* __restrict__ Kf,
    const unsigned short* __restrict__ Vf,
    const unsigned char* __restrict__ mask,
    float* __restrict__ Out0,      // d_out (kvh=0 partial, unnormalized)
    float* __restrict__ Out1,      // ws partial (kvh=1)
    float* __restrict__ l0,
    float* __restrict__ l1) {
    __shared__ unsigned short pbuf[4][32 * PLDT];  // per-wave P [32 q][64 kv]

    const int tid = threadIdx.x;
    const int lane = tid & 63;
    const int w = tid >> 6;
    const int lr = lane & 15;
    const int lg = lane >> 4;

    // T1 XCD swizzle: 1024 workgroups, 128 per XCD -> 4 heads' full KV (2MB)
    // per XCD L2.
    const int bid = blockIdx.x;
    const int wk = (bid & 7) * 128 + (bid >> 3);
    const int x = wk & 15;            // q-tile
    const int kvh = (wk >> 4) & 1;    // kv half
    const int bh = wk >> 5;           // 0..31
    const int h = bh & 15;
    const int b = bh >> 4;
    const int q0 = x * 128;

    const size_t headoff = (((size_t)b * 16) + h) * 131072;
    const unsigned short* Qp = Qh + headoff;
    const unsigned char* maskp = mask + b * 2048;
    unsigned short* pw = pbuf[w];

    const unsigned short* kfb = Kf + headoff + (size_t)lane * 8;
    const unsigned short* vfb = Vf + headoff + (size_t)lane * 8;

    // Q as B-operand (col=q=lr, k=lg*8+j), scaled by 1/sqrt(64)*log2(e)
    const float qscale = 0.125f * 1.44269504088896340736f;
    bf16x8 qf[2][2];
#pragma unroll
    for (int qh = 0; qh < 2; ++qh) {
        int row = q0 + w * 32 + qh * 16 + lr;
#pragma unroll
        for (int ks = 0; ks < 2; ++ks) {
            bf16x8 t = *(const bf16x8*)(Qp + (size_t)row * 64 + ks * 32 + lg * 8);
#pragma unroll
            for (int j = 0; j < 8; ++j)
                t[j] = (short)f2bf(bf2f((unsigned short)t[j]) * qscale);
            qf[qh][ks] = t;
        }
    }

    f32x4 o[2][4] = {};           // O^T partial: lane holds q=lr
    float lsum[2] = {0.f, 0.f};

    const int t0 = kvh * 16;
#pragma unroll 1
    for (int t = t0; t < t0 + 16; ++t) {
        const int kv0 = t * 64;
        const unsigned short* kt = kfb + t * 4096;
        const unsigned short* vt = vfb + t * 4096;

        bf16x8 kf[2][4];
#pragma unroll
        for (int ks = 0; ks < 2; ++ks)
#pragma unroll
            for (int mt = 0; mt < 4; ++mt)
                kf[ks][mt] = *(const bf16x8*)(kt + (ks * 4 + mt) * 512);

        f32x4 s[2][4] = {};
        __builtin_amdgcn_s_setprio(1);
#pragma unroll
        for (int ks = 0; ks < 2; ++ks)
#pragma unroll
            for (int mt = 0; mt < 4; ++mt) {
                s[0][mt] = __builtin_amdgcn_mfma_f32_16x16x32_bf16(kf[ks][mt], qf[0][ks], s[0][mt], 0, 0, 0);
                s[1][mt] = __builtin_amdgcn_mfma_f32_16x16x32_bf16(kf[ks][mt], qf[1][ks], s[1][mt], 0, 0, 0);
            }
        __builtin_amdgcn_s_setprio(0);

        bf16x8 vf[2][4];
#pragma unroll
        for (int ks = 0; ks < 2; ++ks)
#pragma unroll
            for (int mt = 0; mt < 4; ++mt)
                vf[ks][mt] = *(const bf16x8*)(vt + (ks * 4 + mt) * 512);

        unsigned long long mbits = __ballot(maskp[kv0 + lane] != 0);
        if (mbits) {
#pragma unroll
            for (int qh = 0; qh < 2; ++qh)
#pragma unroll
                for (int mt = 0; mt < 4; ++mt)
#pragma unroll
                    for (int i = 0; i < 4; ++i)
                        if ((mbits >> (mt * 16 + lg * 4 + i)) & 1ull) s[qh][mt][i] = -1e30f;
        }

#pragma unroll
        for (int qh = 0; qh < 2; ++qh) {
            float p[4][4];
            float ls = 0.f;
#pragma unroll
            for (int mt = 0; mt < 4; ++mt)
#pragma unroll
                for (int i = 0; i < 4; ++i) {
                    p[mt][i] = exp2b(s[qh][mt][i]);
                    ls += p[mt][i];
                }
            ls += __shfl_xor(ls, 16);
            ls += __shfl_xor(ls, 32);
            lsum[qh] += ls;

#pragma unroll
            for (int mt = 0; mt < 4; ++mt) {
                uint2 pr;
                pr.x = cvt_pk_bf16(p[mt][0], p[mt][1]);
                pr.y = cvt_pk_bf16(p[mt][2], p[mt][3]);
                *(uint2*)(&pw[(qh * 16 + lr) * PLDT + mt * 16 + lg * 4]) = pr;
            }
        }

        __builtin_amdgcn_s_setprio(1);
#pragma unroll
        for (int qh = 0; qh < 2; ++qh)
#pragma unroll
            for (int ks = 0; ks < 2; ++ks) {
                bf16x8 pfr = *(const bf16x8*)(&pw[(qh * 16 + lr) * PLDT + ks * 32 + lg * 8]);
#pragma unroll
                for (int mt = 0; mt < 4; ++mt)
                    o[qh][mt] = __builtin_amdgcn_mfma_f32_16x16x32_bf16(vf[ks][mt], pfr, o[qh][mt], 0, 0, 0);
            }
        __builtin_amdgcn_s_setprio(0);
    }

    // epilogue: plain stores of the UNNORMALIZED partial (no atomics).
    float* Obase = kvh ? Out1 : Out0;
    float* lbase = kvh ? l1 : l0;
    float* ep = (float*)pw;
#pragma unroll
    for (int qh = 0; qh < 2; ++qh) {
        if (lane < 16)
            lbase[(size_t)bh * 2048 + q0 + w * 32 + qh * 16 + lane] = lsum[qh];
#pragma unroll
        for (int mt = 0; mt < 4; ++mt)
#pragma unroll
            for (int i = 0; i < 4; ++i)
                ep[lr * 68 + mt * 16 + lg * 4 + i] = o[qh][mt][i];
#pragma unroll
        for (int j = 0; j < 4; ++j) {
            int id = lane + 64 * j;
            int row = id >> 4;
            int c4 = (id & 15) << 2;
            float4 val = *(const float4*)(&ep[row * 68 + c4]);
            *(float4*)(&Obase[((size_t)b * 2048 + q0 + w * 32 + qh * 16 + row) * 1024 + h * 64 + c4]) = val;
        }
    }
}

// ---------------------------------------------------------------------------
// Combine: out[i] = (out[i] + part1[i]) / (l0[row] + l1[row]).
// 1048576 float4s; grid 4096 x 256, guarded.
// ---------------------------------------------------------------------------
__global__ __launch_bounds__(256) void combine_out(float* __restrict__ out,
                                                   const float* __restrict__ part1,
                                                   const float* __restrict__ l0,
                                                   const float* __restrict__ l1) {
    int i = blockIdx.x * 256 + threadIdx.x;   // float4 index
    if (i >= 1048576) return;
    int m = i >> 8;                           // b*2048 + s
    int h = (i >> 4) & 15;
    int b = m >> 11, s = m & 2047;
    size_t li = (((size_t)b * 16) + h) * 2048 + s;
    float r = 1.0f / (l0[li] + l1[li]);
    float4 v0 = ((const float4*)out)[i];
    float4 v1 = ((const float4*)part1)[i];
    v0.x = (v0.x + v1.x) * r;
    v0.y = (v0.y + v1.y) * r;
    v0.z = (v0.z + v1.z) * r;
    v0.w = (v0.w + v1.w) * r;
    ((float4*)out)[i] = v0;
}

extern "C" void kernel_launch(void* const* d_in, const int* in_sizes, int n_in,
                              void* d_out, int out_size, void* d_ws, size_t ws_size,
                              hipStream_t stream) {
    const float* v = (const float*)d_in[0];
    const float* k = (const float*)d_in[1];
    const float* q = (const float*)d_in[2];
    const unsigned char* mask = (const unsigned char*)d_in[3];
    const float* Wq = (const float*)d_in[4];
    const float* bq = (const float*)d_in[5];
    const float* Wk = (const float*)d_in[6];
    const float* bk = (const float*)d_in[7];
    const float* Wv = (const float*)d_in[8];
    const float* bv = (const float*)d_in[9];
    float* out = (float*)d_out;

    unsigned short* ws = (unsigned short*)d_ws;
    unsigned short* qh  = ws;                 // 4096*1024 each
    unsigned short* kh  = ws + 4194304;       // K in fragment order
    unsigned short* vT  = ws + 8388608;       // V^T in fragment order
    unsigned short* xqb = ws + 12582912;      // bf16 X inputs (dead after proj)
    unsigned short* xkb = ws + 16777216;
    unsigned short* xvb = ws + 20971520;
    unsigned short* wqb = ws + 25165824;      // bf16 W inputs (dead after proj)
    unsigned short* wkb = ws + 26214400;
    unsigned short* wvb = ws + 27262976;
    // After proj, xqb..xvb are dead: reuse for the kvh=1 partial (16.8MB fits
    // exactly in xqb+xkb) and the two lsum buffers (in xvb). Footprint
    // unchanged at the proven 56.6MB.
    float* part1 = (float*)xqb;               // 4194304 floats = 16.8MB
    float* l0    = (float*)xvb;               // 65536 floats
    float* l1    = l0 + 65536;                // 65536 floats

    cvt_all<<<dim3(2048, 1, 6), 256, 0, stream>>>(q, k, v, Wq, Wk, Wv,
                                                  xqb, xkb, xvb, wqb, wkb, wvb);

    dim3 pgrid(32, 8, 3);
    proj_gemm_bf16<<<pgrid, 256, 0, stream>>>(xqb, xkb, xvb, wqb, wkb, wvb,
                                              bq, bk, bv, qh, kh, vT);

    attn_kernel<<<dim3(1024), 256, 0, stream>>>(qh, kh, vT, mask,
                                                out, part1, l0, l1);

    combine_out<<<dim3(4096), 256, 0, stream>>>(out, part1, l0, l1);
}